// Round 1
// baseline (68.022 us; speedup 1.0000x reference)
//
#include <hip/hip_runtime.h>
#include <hip/hip_bf16.h>

typedef __bf16 bf16x8 __attribute__((ext_vector_type(8)));
typedef float  f32x4  __attribute__((ext_vector_type(4)));

#define MFMA16(a,b,c) __builtin_amdgcn_mfma_f32_16x16x32_bf16((a),(b),(c),0,0,0)

constexpr int Bn = 8192, Dd = 64, MT = 16;

// ws image layout (bytes), produced once by prep_kernel:
//   W1b [128][72]us @0       (GEMM1 B-frags, row-major W1[j][d], pitch 72)
//   Wfb [64][72]us  @18432   (GEMM3 B-frags, row-major Wf[i][d])
//   W1T [64][136]us @27648   (GEMM2 B-frags, W1T[d][j])
//   b1  [128]f32    @45056
//   W2  [128]f32    @45568
constexpr int OFF_WFB = 18432, OFF_W1T = 27648, OFF_B1 = 45056;

__device__ __forceinline__ unsigned short f2bf(float f) {
    unsigned int u = __builtin_bit_cast(unsigned int, f);
    u = (u + 0x7FFFu + ((u >> 16) & 1u)) >> 16;   // RNE
    return (unsigned short)u;
}

__device__ __forceinline__ bf16x8 pack8(float4 a, float4 b) {
    union { bf16x8 v; unsigned short u[8]; } r;
    r.u[0] = f2bf(a.x); r.u[1] = f2bf(a.y); r.u[2] = f2bf(a.z); r.u[3] = f2bf(a.w);
    r.u[4] = f2bf(b.x); r.u[5] = f2bf(b.y); r.u[6] = f2bf(b.z); r.u[7] = f2bf(b.w);
    return r.v;
}

// One-time (per call) weight repack: fp32 -> bf16 image in ws (global).
__global__ __launch_bounds__(256) void prep_kernel(
    const float* __restrict__ W1, const float* __restrict__ b1,
    const float* __restrict__ W2, const float* __restrict__ Wf,
    unsigned short* __restrict__ ws)
{
    int i = blockIdx.x * 256 + threadIdx.x;
    unsigned short* W1b = ws;
    unsigned short* Wfb = ws + OFF_WFB / 2;
    unsigned short* W1T = ws + OFF_W1T / 2;
    float* bw = (float*)(ws + OFF_B1 / 2);
    if (i < 2048) {
        float4 v = ((const float4*)W1)[i];
        int e = i << 2, j = e >> 6, d = e & 63;
        unsigned short c0 = f2bf(v.x), c1 = f2bf(v.y), c2 = f2bf(v.z), c3 = f2bf(v.w);
        *(ushort4*)(W1b + j * 72 + d) = make_ushort4(c0, c1, c2, c3);
        W1T[(d + 0) * 136 + j] = c0;
        W1T[(d + 1) * 136 + j] = c1;
        W1T[(d + 2) * 136 + j] = c2;
        W1T[(d + 3) * 136 + j] = c3;
    } else if (i < 3072) {
        int k = i - 2048;
        float4 v = ((const float4*)Wf)[k];
        int e = k << 2, j = e >> 6, d = e & 63;
        *(ushort4*)(Wfb + j * 72 + d) =
            make_ushort4(f2bf(v.x), f2bf(v.y), f2bf(v.z), f2bf(v.w));
    } else if (i < 3200) {
        bw[i - 3072] = b1[i - 3072];
    } else if (i < 3328) {
        bw[128 + i - 3200] = W2[i - 3200];
    }
}

// Main kernel: weights consumed as per-lane 16B frag loads straight from the
// L2-resident global image (no LDS weight staging, no image DMA, no Zb tile).
// LDS holds only the G redistribution buffer (16x136 us = 4352 B).
__global__ __launch_bounds__(256) void gnl_kernel(
    const float* __restrict__ z, const unsigned short* __restrict__ wsimg,
    float* __restrict__ out)
{
    __shared__ unsigned short Gb[MT * 136];            // [16][136]

    const int tid  = threadIdx.x;
    const int lane = tid & 63, wv = tid >> 6;
    const int l15 = lane & 15, q = lane >> 4;
    const int row0 = blockIdx.x * MT;

    const unsigned short* W1b = wsimg;
    const unsigned short* Wfb = wsimg + OFF_WFB / 2;
    const unsigned short* W1T = wsimg + OFF_W1T / 2;
    const float* b1f = (const float*)(wsimg + OFF_B1 / 2);
    const float* w2f = b1f + 128;

    // ---- A-frags: coalesced fp32 z loads -> bf16 pack in regs ----
    // A[m=l15][k=q*8+j]; za0 covers k 0..31, za1 covers k 32..63.
    const float* zp = z + (size_t)(row0 + l15) * Dd + q * 8;
    float4 f0 = *(const float4*)(zp + 0);
    float4 f1 = *(const float4*)(zp + 4);
    float4 f2 = *(const float4*)(zp + 32);
    float4 f3 = *(const float4*)(zp + 36);
    bf16x8 za0 = pack8(f0, f1);
    bf16x8 za1 = pack8(f2, f3);

    // ---- GEMM1: U = Z*W1^T (K=64), fused g = W2*silu'(u+b1) -> Gb ----
    // 8 N-tiles split across 4 waves (2 each). B-frags direct from global.
    #pragma unroll
    for (int nt = 0; nt < 2; ++nt) {
        const int jc = (wv * 2 + nt) * 16 + l15;       // column j of U
        const unsigned short* wp = W1b + jc * 72 + q * 8;
        f32x4 acc = {0.f, 0.f, 0.f, 0.f};
        acc = MFMA16(za0, *(const bf16x8*)wp, acc);
        acc = MFMA16(za1, *(const bf16x8*)(wp + 32), acc);
        const float bj = b1f[jc], w2j = w2f[jc];
        #pragma unroll
        for (int r = 0; r < 4; ++r) {                  // C: row=q*4+r, col=jc
            float u = acc[r] + bj;
            float s = 1.f / (1.f + __expf(-u));
            float g = w2j * (s * (1.f + u * (1.f - s)));   // W2 * silu'(u)
            Gb[(q * 4 + r) * 136 + jc] = f2bf(g);
        }
    }
    __syncthreads();

    // ---- GEMM2: GS = G*W1 (K=128); GEMM3: A = Z*Wf^T (K=64); epilogue ----
    const int goff = l15 * 136 + q * 8;
    bf16x8 ga0 = *(const bf16x8*)(Gb + goff);
    bf16x8 ga1 = *(const bf16x8*)(Gb + goff + 32);
    bf16x8 ga2 = *(const bf16x8*)(Gb + goff + 64);
    bf16x8 ga3 = *(const bf16x8*)(Gb + goff + 96);

    const int dc = wv * 16 + l15;                      // output dim d (1 tile/wave)
    const unsigned short* wt = W1T + dc * 136 + q * 8;
    f32x4 gs = {0.f, 0.f, 0.f, 0.f};
    gs = MFMA16(ga0, *(const bf16x8*)wt, gs);
    gs = MFMA16(ga1, *(const bf16x8*)(wt + 32), gs);
    gs = MFMA16(ga2, *(const bf16x8*)(wt + 64), gs);
    gs = MFMA16(ga3, *(const bf16x8*)(wt + 96), gs);

    const unsigned short* wfp = Wfb + dc * 72 + q * 8;
    f32x4 av = {0.f, 0.f, 0.f, 0.f};
    av = MFMA16(za0, *(const bf16x8*)wfp, av);
    av = MFMA16(za1, *(const bf16x8*)(wfp + 32), av);

    const bool  lo  = dc < 32;                         // wave-uniform
    const int   src = lo ? dc + 32 : dc - 32;
    const float sgn = lo ? 1.f : -1.f;
    #pragma unroll
    for (int r = 0; r < 4; ++r) {
        const int rr = row0 + q * 4 + r;               // global row
        float rev = sgn * z[(size_t)rr * Dd + src];    // fp32-exact reversible
        float a = av[r];
        out[(size_t)rr * Dd + dc] = rev + a * a * gs[r];
    }
}

extern "C" void kernel_launch(void* const* d_in, const int* in_sizes, int n_in,
                              void* d_out, int out_size, void* d_ws, size_t ws_size,
                              hipStream_t stream)
{
    const float* z  = (const float*)d_in[0];
    const float* W1 = (const float*)d_in[1];
    const float* b1 = (const float*)d_in[2];
    const float* W2 = (const float*)d_in[3];
    // d_in[4] = b2: unused — gradient w.r.t. z is independent of b2
    const float* Wf = (const float*)d_in[5];
    float* out = (float*)d_out;
    unsigned short* ws = (unsigned short*)d_ws;

    prep_kernel<<<13, 256, 0, stream>>>(W1, b1, W2, Wf, ws);
    gnl_kernel<<<Bn / MT, 256, 0, stream>>>(z, ws, out);
}